// Round 10
// baseline (277.370 us; speedup 1.0000x reference)
//
#include <hip/hip_runtime.h>

// GeodesicShooting on [160^3,3] f32, AoS layout.
// z/y blur: R1's EXACT naive kernel (runtime 9-tap loop, branch-skip, VGPR~8,
// max occupancy) — measured ~22 us/pass in R1; every "smarter" variant since
// (unroll/window/LDS/MLP-batch) regressed to 40-50 us. Do not "improve" it.
// x blur: 4-voxel float4 window (~15 us). Steps: R4 MLP gather + R5 XCD swizzle
// (~22-25 us, at traffic floor).
// Identity grid folded analytically into steps: s = idx + 79.5*v.
// Parity: z vel->OUT ; y OUT->WS ; x WS->OUT(scale) ; steps OUT->WS->...->OUT.

constexpr int W = 160, H = 160, D = 160;
constexpr int NVOX = W * H * D;           // 4,096,000
constexpr int NSTEPS = 6;
constexpr float HSC = 79.5f;              // 0.5*(W-1)

__device__ __forceinline__ int iclamp(int v, int lo, int hi) {
    return v < lo ? lo : (v > hi ? hi : v);
}

// ---- blur along one axis (R1 verbatim): runtime loop, branch-skip ----
// coordinate along axis = (i / div) % len ; neighbor step = strideVox voxels
__global__ void blur_axis_kernel(const float* __restrict__ in, float* __restrict__ out,
                                 const float* __restrict__ kern, int klen,
                                 int len, int div, int strideVox, float scale)
{
    int i = blockIdx.x * blockDim.x + threadIdx.x;
    if (i >= NVOX) return;
    int c = (i / div) % len;
    int R = (klen - 1) / 2;
    float ax = 0.f, ay = 0.f, az = 0.f;
    for (int t = 0; t < klen; ++t) {
        int cc = c + t - R;
        if (cc < 0 || cc >= len) continue;           // zero padding
        const float* p = in + (size_t)(i + (t - R) * strideVox) * 3;
        float w = kern[t];
        ax = fmaf(w, p[0], ax);
        ay = fmaf(w, p[1], ay);
        az = fmaf(w, p[2], az);
    }
    float* q = out + (size_t)i * 3;
    q[0] = ax * scale;
    q[1] = ay * scale;
    q[2] = az * scale;
}

// ---- blur along x (+ 2^-6 scale): 4 voxels/thread, 9 float4 window loads ----
__global__ void blur_x_vec4(const float* __restrict__ in, float* __restrict__ out,
                            const float* __restrict__ gk, float scale)
{
    int tid = blockIdx.x * blockDim.x + threadIdx.x;    // 1,024,000 threads
    if (tid >= NVOX / 4) return;
    int nx4 = W / 4;                                     // 40
    int x0 = (tid % nx4) * 4;
    int row = tid / nx4;                                 // (z*H + y)
    size_t rowBase = (size_t)row * W * 3;

    float kw[9];
#pragma unroll
    for (int t = 0; t < 9; ++t) kw[t] = gk[t];

    long f0 = (long)rowBase + (long)(x0 - 4) * 3;        // may be negative at x0==0
    const long maxF4 = (long)NVOX * 3 - 4;
    float wv[36];
#pragma unroll
    for (int k = 0; k < 9; ++k) {
        long a = f0 + 4 * k;
        a = a < 0 ? 0 : (a > maxF4 ? maxF4 : a);
        float4 v4 = *(const float4*)(in + a);
        wv[4 * k + 0] = v4.x; wv[4 * k + 1] = v4.y;
        wv[4 * k + 2] = v4.z; wv[4 * k + 3] = v4.w;
    }
#pragma unroll
    for (int m = 0; m < 12; ++m) {
        int xi = x0 - 4 + m;
        if (xi < 0 || xi >= W) { wv[3 * m] = 0.f; wv[3 * m + 1] = 0.f; wv[3 * m + 2] = 0.f; }
    }

    float o[12];
#pragma unroll
    for (int j = 0; j < 4; ++j) {
#pragma unroll
        for (int cth = 0; cth < 3; ++cth) {
            float s = 0.f;
#pragma unroll
            for (int t = 0; t < 9; ++t) s = fmaf(kw[t], wv[3 * (j + t) + cth], s);
            o[3 * j + cth] = s * scale;
        }
    }
    float4* q = (float4*)(out + rowBase + (size_t)x0 * 3);
    q[0] = make_float4(o[0], o[1], o[2],  o[3]);
    q[1] = make_float4(o[4], o[5], o[6],  o[7]);
    q[2] = make_float4(o[8], o[9], o[10], o[11]);
}

// ---- one scaling-and-squaring step: out = v + trilerp(v, id + v), AoS ----
__global__ void step_kernel(const float* __restrict__ v, float* __restrict__ out)
{
    int b = blockIdx.x;
    int bs = (b & 7) * 2000 + (b >> 3);                 // bijective XCD swizzle
    int i = bs * blockDim.x + threadIdx.x;
    int x = i % W;
    int t = i / W;
    int y = t % H;
    int z = t / H;

    const float* pv = v + (size_t)i * 3;
    float vx = pv[0], vy = pv[1], vz = pv[2];

    float sx = fmaf(vx, HSC, (float)x);
    float sy = fmaf(vy, HSC, (float)y);
    float sz = fmaf(vz, HSC, (float)z);

    float fx = floorf(sx), fy = floorf(sy), fz = floorf(sz);
    int x0 = (int)fx, y0 = (int)fy, z0 = (int)fz;
    float wx1 = sx - fx, wy1 = sy - fy, wz1 = sz - fz;
    float wx0 = 1.f - wx1, wy0 = 1.f - wy1, wz0 = 1.f - wz1;

    wx0 *= (x0     >= 0 && x0     < W) ? 1.f : 0.f;
    wx1 *= (x0 + 1 >= 0 && x0 + 1 < W) ? 1.f : 0.f;
    wy0 *= (y0     >= 0 && y0     < H) ? 1.f : 0.f;
    wy1 *= (y0 + 1 >= 0 && y0 + 1 < H) ? 1.f : 0.f;
    wz0 *= (z0     >= 0 && z0     < D) ? 1.f : 0.f;
    wz1 *= (z0 + 1 >= 0 && z0 + 1 < D) ? 1.f : 0.f;

    int xc0 = iclamp(x0, 0, W - 1), xc1 = iclamp(x0 + 1, 0, W - 1);
    int yc0 = iclamp(y0, 0, H - 1), yc1 = iclamp(y0 + 1, 0, H - 1);
    int zc0 = iclamp(z0, 0, D - 1), zc1 = iclamp(z0 + 1, 0, D - 1);

    int idx[8];
    idx[0] = (zc0 * H + yc0) * W + xc0;
    idx[1] = (zc0 * H + yc0) * W + xc1;
    idx[2] = (zc0 * H + yc1) * W + xc0;
    idx[3] = (zc0 * H + yc1) * W + xc1;
    idx[4] = (zc1 * H + yc0) * W + xc0;
    idx[5] = (zc1 * H + yc0) * W + xc1;
    idx[6] = (zc1 * H + yc1) * W + xc0;
    idx[7] = (zc1 * H + yc1) * W + xc1;

    float c[8][3];
#pragma unroll
    for (int k = 0; k < 8; ++k) {
        const float* p = v + (size_t)idx[k] * 3;
        c[k][0] = p[0];
        c[k][1] = p[1];
        c[k][2] = p[2];
    }

    float w8[8];
    w8[0] = wz0 * wy0 * wx0;
    w8[1] = wz0 * wy0 * wx1;
    w8[2] = wz0 * wy1 * wx0;
    w8[3] = wz0 * wy1 * wx1;
    w8[4] = wz1 * wy0 * wx0;
    w8[5] = wz1 * wy0 * wx1;
    w8[6] = wz1 * wy1 * wx0;
    w8[7] = wz1 * wy1 * wx1;

    float r0 = vx, r1 = vy, r2 = vz;
#pragma unroll
    for (int k = 0; k < 8; ++k) {
        r0 = fmaf(w8[k], c[k][0], r0);
        r1 = fmaf(w8[k], c[k][1], r1);
        r2 = fmaf(w8[k], c[k][2], r2);
    }

    float* q = out + (size_t)i * 3;
    q[0] = r0;
    q[1] = r1;
    q[2] = r2;
}

extern "C" void kernel_launch(void* const* d_in, const int* in_sizes, int n_in,
                              void* d_out, int out_size, void* d_ws, size_t ws_size,
                              hipStream_t stream)
{
    const float* vel = (const float*)d_in[0];
    // d_in[1] (identity grid) folded analytically
    const float* gk  = (const float*)d_in[2];
    int klen = in_sizes[2];                     // 9

    float* OUT = (float*)d_out;
    float* WS  = (float*)d_ws;                  // one [NVOX,3] f32 buffer

    const int threads = 256;
    const int voxBlocks = NVOX / threads;               // 16000
    const int x4Blocks  = (NVOX / 4) / threads;         // 4000
    const float scale = 1.0f / (float)(1 << NSTEPS);    // 2^-6

    // blur: z (vel->OUT), y (OUT->WS) — R1 kernel; x+scale (WS->OUT) — vec4
    blur_axis_kernel<<<voxBlocks, threads, 0, stream>>>(vel, OUT, gk, klen, D, W * H, W * H, 1.0f);
    blur_axis_kernel<<<voxBlocks, threads, 0, stream>>>(OUT, WS, gk, klen, H, W, W, 1.0f);
    blur_x_vec4<<<x4Blocks, threads, 0, stream>>>(WS, OUT, gk, scale);

    // 6 squaring steps: OUT -> WS -> OUT -> WS -> OUT -> WS -> OUT
    step_kernel<<<voxBlocks, threads, 0, stream>>>(OUT, WS);
    step_kernel<<<voxBlocks, threads, 0, stream>>>(WS, OUT);
    step_kernel<<<voxBlocks, threads, 0, stream>>>(OUT, WS);
    step_kernel<<<voxBlocks, threads, 0, stream>>>(WS, OUT);
    step_kernel<<<voxBlocks, threads, 0, stream>>>(OUT, WS);
    step_kernel<<<voxBlocks, threads, 0, stream>>>(WS, OUT);
}

// Round 11
// 240.471 us; speedup vs baseline: 1.1534x; 1.1534x over previous
//
#include <hip/hip_runtime.h>

// GeodesicShooting on [160^3,3] f32, AoS layout.
// Structure = R8 (best, 239 us) with all-b128 LDS blur kernels:
//   z-blur: LDS slab [16][480]f staged as float4; compute 4 voxels/unit
//   yx-blur fused: LDS plane tile, float4 staging + b128 tap reads
//   steps: R4 MLP gather + XCD swizzle (proven ~24 us, near roofline)
// Identity grid folded analytically: s = idx + 79.5*v.
// Parity: z vel->WS ; yx WS->OUT(scale) ; steps OUT->WS->...->OUT (6 steps).

constexpr int W = 160, H = 160, D = 160;
constexpr int NVOX = W * H * D;            // 4,096,000
constexpr int NSTEPS = 6;
constexpr float HSC = 79.5f;               // 0.5*(W-1)

constexpr int ZT = 8;                      // z outputs per block
constexpr int ZR = ZT + 8;                 // 16 staged z-rows

constexpr int YT = 8;                      // y outputs per block
constexpr int XT = 80;                     // x outputs per block (half row)
constexpr int YR = YT + 8;                 // 16 staged rows
constexpr int XRG = 22;                    // staged 4-voxel col groups (88 voxels)
constexpr int XOG = 20;                    // output 4-voxel col groups (80 voxels)

__device__ __forceinline__ int iclamp(int v, int lo, int hi) {
    return v < lo ? lo : (v > hi ? hi : v);
}

// ---- blur along z: LDS slab, float4 staging, 4-voxel compute groups ----
__global__ void blur_z_lds4(const float* __restrict__ in, float* __restrict__ out,
                            const float* __restrict__ gk)
{
    __shared__ float4 raw[ZR][120];        // 16 z-rows x 480 floats = 30,720 B

    int b = blockIdx.x;
    int bs = (b & 7) * 400 + (b >> 3);     // 3200 blocks, bijective XCD swizzle
    int y    = bs % H;
    int zseg = bs / H;                     // 0..19
    int z0 = zseg * ZT;

    float kw[9];
#pragma unroll
    for (int t = 0; t < 9; ++t) kw[t] = gk[t];

    // stage 16 z-rows as float4 (each row: 120 float4, contiguous in global)
    for (int j = threadIdx.x; j < ZR * 120; j += 256) {
        int col = j % 120;
        int zr  = j / 120;
        int zz = z0 - 4 + zr;
        bool ok = (zz >= 0) && (zz < D);
        const float4* p = (const float4*)(in + ((size_t)iclamp(zz, 0, D - 1) * H + y) * 480);
        raw[zr][col] = ok ? p[col] : make_float4(0.f, 0.f, 0.f, 0.f);
    }
    __syncthreads();

    // compute 8 z x 40 col-groups (4 voxels each): 27 b128 LDS reads + 108 FMA
    for (int j = threadIdx.x; j < ZT * 40; j += 256) {
        int xg = j % 40;
        int t  = j / 40;
        float a[12] = {0,0,0,0,0,0,0,0,0,0,0,0};
#pragma unroll
        for (int k = 0; k < 9; ++k) {
            const float4* r = &raw[t + k][xg * 3];
            float4 u0 = r[0], u1 = r[1], u2 = r[2];
            float w = kw[k];
            a[0]  = fmaf(w, u0.x, a[0]);  a[1]  = fmaf(w, u0.y, a[1]);
            a[2]  = fmaf(w, u0.z, a[2]);  a[3]  = fmaf(w, u0.w, a[3]);
            a[4]  = fmaf(w, u1.x, a[4]);  a[5]  = fmaf(w, u1.y, a[5]);
            a[6]  = fmaf(w, u1.z, a[6]);  a[7]  = fmaf(w, u1.w, a[7]);
            a[8]  = fmaf(w, u2.x, a[8]);  a[9]  = fmaf(w, u2.y, a[9]);
            a[10] = fmaf(w, u2.z, a[10]); a[11] = fmaf(w, u2.w, a[11]);
        }
        float4* q = (float4*)(out + ((size_t)(z0 + t) * H + y) * 480 + (size_t)xg * 12);
        q[0] = make_float4(a[0], a[1], a[2],  a[3]);
        q[1] = make_float4(a[4], a[5], a[6],  a[7]);
        q[2] = make_float4(a[8], a[9], a[10], a[11]);
    }
}

// ---- fused y-blur + x-blur (+ 2^-6 scale), float4/b128 throughout ----
__global__ void blur_yx_lds4(const float* __restrict__ in, float* __restrict__ out,
                             const float* __restrict__ gk, float scale)
{
    __shared__ float4 raw[YR][XRG * 3];    // 16 x 66 float4 = 16,896 B
    __shared__ float4 yb [YT][XRG * 3];    //  8 x 66 float4 =  8,448 B

    int b = blockIdx.x;
    int bs = (b & 7) * 800 + (b >> 3);     // 6400 blocks, bijective
    int xh   = bs % 2;
    int t2   = bs / 2;
    int yseg = t2 % 20;
    int z    = t2 / 20;
    int y0 = yseg * YT;
    int x0 = xh * XT;

    float kw[9];
#pragma unroll
    for (int t = 0; t < 9; ++t) kw[t] = gk[t];

    const size_t planeBase = (size_t)z * H * W * 3;    // floats

    // stage: 16 rows x 22 groups; each group = 4 voxels = 3 float4.
    // Groups are fully-valid or fully-invalid: x0-4+4g in [0,156] when valid.
    for (int j = threadIdx.x; j < YR * XRG; j += 256) {
        int g   = j % XRG;
        int row = j / XRG;
        int yy = y0 - 4 + row;
        int xb = x0 - 4 + g * 4;
        bool ok = (yy >= 0) && (yy < H) && (xb >= 0) && (xb <= W - 4);
        const float4* p = (const float4*)(in + planeBase +
            ((size_t)iclamp(yy, 0, H - 1) * W + iclamp(xb, 0, W - 4)) * 3);
        float4 z4 = make_float4(0.f, 0.f, 0.f, 0.f);
        raw[row][g * 3 + 0] = ok ? p[0] : z4;
        raw[row][g * 3 + 1] = ok ? p[1] : z4;
        raw[row][g * 3 + 2] = ok ? p[2] : z4;
    }
    __syncthreads();

    // y-blur: 8 rows x 22 groups
    for (int j = threadIdx.x; j < YT * XRG; j += 256) {
        int g   = j % XRG;
        int row = j / XRG;
        float a[12] = {0,0,0,0,0,0,0,0,0,0,0,0};
#pragma unroll
        for (int k = 0; k < 9; ++k) {
            float4 u0 = raw[row + k][g * 3 + 0];
            float4 u1 = raw[row + k][g * 3 + 1];
            float4 u2 = raw[row + k][g * 3 + 2];
            float w = kw[k];
            a[0]  = fmaf(w, u0.x, a[0]);  a[1]  = fmaf(w, u0.y, a[1]);
            a[2]  = fmaf(w, u0.z, a[2]);  a[3]  = fmaf(w, u0.w, a[3]);
            a[4]  = fmaf(w, u1.x, a[4]);  a[5]  = fmaf(w, u1.y, a[5]);
            a[6]  = fmaf(w, u1.z, a[6]);  a[7]  = fmaf(w, u1.w, a[7]);
            a[8]  = fmaf(w, u2.x, a[8]);  a[9]  = fmaf(w, u2.y, a[9]);
            a[10] = fmaf(w, u2.z, a[10]); a[11] = fmaf(w, u2.w, a[11]);
        }
        yb[row][g * 3 + 0] = make_float4(a[0], a[1], a[2],  a[3]);
        yb[row][g * 3 + 1] = make_float4(a[4], a[5], a[6],  a[7]);
        yb[row][g * 3 + 2] = make_float4(a[8], a[9], a[10], a[11]);
    }
    __syncthreads();

    // x-blur + scale: 8 rows x 20 output groups; window = 9 float4 (12 voxels)
    for (int j = threadIdx.x; j < YT * XOG; j += 256) {
        int xg = j % XOG;
        int yo = j / XOG;
        float wv[36];
#pragma unroll
        for (int m = 0; m < 9; ++m) {
            float4 u = yb[yo][xg * 3 + m];
            wv[4 * m + 0] = u.x; wv[4 * m + 1] = u.y;
            wv[4 * m + 2] = u.z; wv[4 * m + 3] = u.w;
        }
        // output voxel xo = xg*4 + jj uses window voxels xo..xo+8 (halo offset -4)
        float o[12];
#pragma unroll
        for (int jj = 0; jj < 4; ++jj) {
#pragma unroll
            for (int cth = 0; cth < 3; ++cth) {
                float s = 0.f;
#pragma unroll
                for (int t = 0; t < 9; ++t)
                    s = fmaf(kw[t], wv[3 * (jj + t) + cth], s);
                o[3 * jj + cth] = s * scale;
            }
        }
        float4* q = (float4*)(out + planeBase +
            ((size_t)(y0 + yo) * W + (x0 + xg * 4)) * 3);
        q[0] = make_float4(o[0], o[1], o[2],  o[3]);
        q[1] = make_float4(o[4], o[5], o[6],  o[7]);
        q[2] = make_float4(o[8], o[9], o[10], o[11]);
    }
}

// ---- one scaling-and-squaring step: out = v + trilerp(v, id + v), AoS ----
__global__ void step_kernel(const float* __restrict__ v, float* __restrict__ out)
{
    int b = blockIdx.x;
    int bs = (b & 7) * 2000 + (b >> 3);                 // bijective XCD swizzle
    int i = bs * blockDim.x + threadIdx.x;
    int x = i % W;
    int t = i / W;
    int y = t % H;
    int z = t / H;

    const float* pv = v + (size_t)i * 3;
    float vx = pv[0], vy = pv[1], vz = pv[2];

    float sx = fmaf(vx, HSC, (float)x);
    float sy = fmaf(vy, HSC, (float)y);
    float sz = fmaf(vz, HSC, (float)z);

    float fx = floorf(sx), fy = floorf(sy), fz = floorf(sz);
    int x0 = (int)fx, y0 = (int)fy, z0 = (int)fz;
    float wx1 = sx - fx, wy1 = sy - fy, wz1 = sz - fz;
    float wx0 = 1.f - wx1, wy0 = 1.f - wy1, wz0 = 1.f - wz1;

    wx0 *= (x0     >= 0 && x0     < W) ? 1.f : 0.f;
    wx1 *= (x0 + 1 >= 0 && x0 + 1 < W) ? 1.f : 0.f;
    wy0 *= (y0     >= 0 && y0     < H) ? 1.f : 0.f;
    wy1 *= (y0 + 1 >= 0 && y0 + 1 < H) ? 1.f : 0.f;
    wz0 *= (z0     >= 0 && z0     < D) ? 1.f : 0.f;
    wz1 *= (z0 + 1 >= 0 && z0 + 1 < D) ? 1.f : 0.f;

    int xc0 = iclamp(x0, 0, W - 1), xc1 = iclamp(x0 + 1, 0, W - 1);
    int yc0 = iclamp(y0, 0, H - 1), yc1 = iclamp(y0 + 1, 0, H - 1);
    int zc0 = iclamp(z0, 0, D - 1), zc1 = iclamp(z0 + 1, 0, D - 1);

    int idx[8];
    idx[0] = (zc0 * H + yc0) * W + xc0;
    idx[1] = (zc0 * H + yc0) * W + xc1;
    idx[2] = (zc0 * H + yc1) * W + xc0;
    idx[3] = (zc0 * H + yc1) * W + xc1;
    idx[4] = (zc1 * H + yc0) * W + xc0;
    idx[5] = (zc1 * H + yc0) * W + xc1;
    idx[6] = (zc1 * H + yc1) * W + xc0;
    idx[7] = (zc1 * H + yc1) * W + xc1;

    float c[8][3];
#pragma unroll
    for (int k = 0; k < 8; ++k) {
        const float* p = v + (size_t)idx[k] * 3;
        c[k][0] = p[0];
        c[k][1] = p[1];
        c[k][2] = p[2];
    }

    float w8[8];
    w8[0] = wz0 * wy0 * wx0;
    w8[1] = wz0 * wy0 * wx1;
    w8[2] = wz0 * wy1 * wx0;
    w8[3] = wz0 * wy1 * wx1;
    w8[4] = wz1 * wy0 * wx0;
    w8[5] = wz1 * wy0 * wx1;
    w8[6] = wz1 * wy1 * wx0;
    w8[7] = wz1 * wy1 * wx1;

    float r0 = vx, r1 = vy, r2 = vz;
#pragma unroll
    for (int k = 0; k < 8; ++k) {
        r0 = fmaf(w8[k], c[k][0], r0);
        r1 = fmaf(w8[k], c[k][1], r1);
        r2 = fmaf(w8[k], c[k][2], r2);
    }

    float* q = out + (size_t)i * 3;
    q[0] = r0;
    q[1] = r1;
    q[2] = r2;
}

extern "C" void kernel_launch(void* const* d_in, const int* in_sizes, int n_in,
                              void* d_out, int out_size, void* d_ws, size_t ws_size,
                              hipStream_t stream)
{
    const float* vel = (const float*)d_in[0];
    // d_in[1] (identity grid) folded analytically
    const float* gk  = (const float*)d_in[2];   // 9 taps

    float* OUT = (float*)d_out;
    float* WS  = (float*)d_ws;                  // one [NVOX,3] f32 buffer

    const int threads = 256;
    const int zBlocks   = H * (D / ZT);                     // 3200
    const int yxBlocks  = D * (H / YT) * (W / XT);          // 6400
    const int stepBlocks = NVOX / threads;                  // 16000
    const float scale = 1.0f / (float)(1 << NSTEPS);        // 2^-6

    // blur: vel -> WS (z), WS -> OUT (y+x fused, scaled)
    blur_z_lds4 <<<zBlocks,  threads, 0, stream>>>(vel, WS, gk);
    blur_yx_lds4<<<yxBlocks, threads, 0, stream>>>(WS, OUT, gk, scale);

    // 6 squaring steps: OUT -> WS -> OUT -> WS -> OUT -> WS -> OUT
    step_kernel<<<stepBlocks, threads, 0, stream>>>(OUT, WS);
    step_kernel<<<stepBlocks, threads, 0, stream>>>(WS, OUT);
    step_kernel<<<stepBlocks, threads, 0, stream>>>(OUT, WS);
    step_kernel<<<stepBlocks, threads, 0, stream>>>(WS, OUT);
    step_kernel<<<stepBlocks, threads, 0, stream>>>(OUT, WS);
    step_kernel<<<stepBlocks, threads, 0, stream>>>(WS, OUT);
}